// Round 2
// baseline (4284.709 us; speedup 1.0000x reference)
//
#include <hip/hip_runtime.h>

// RNN1DGeneral: B=256, L=4096, HIDDEN=128, DEPTH=2, INPUT_DIM=2
// One block per batch (256 blocks = 256 CUs), 512 threads/block.
// Weights held in registers (64 fp32/thread); h vectors broadcast via LDS.
// One __syncthreads per time step; layer0@t and layer1@t computed in parallel
// (h1[t] = elu(h1[t-1]@W1) + h0[t], with h0[t] passed by shfl_xor(.,2)).

#define L_LEN 4096
#define HID   128
#define TPB   512

__global__ __launch_bounds__(TPB, 1)
void rnn_fused_kernel(const int*   __restrict__ x,
                      const float* __restrict__ W_in,
                      const float* __restrict__ W_c,
                      const float* __restrict__ W_out,
                      const float* __restrict__ b_out,
                      float*       __restrict__ out)
{
    __shared__ int   xsm[L_LEN];           // 16 KB: this batch's spin sequence
    __shared__ float Rsm[2 * HID];         // elu(W_in) rows, precomputed
    __shared__ float hbuf[2][2][132];      // [parity][layer][H + pad]
    __shared__ float gpart[2][8];          // per-wave logit partials, dbuf
    __shared__ float accbuf[8];            // final per-wave log-prob sums

    const int T     = threadIdx.x;
    const int b     = blockIdx.x;
    const int m     = T >> 2;          // output index 0..127
    const int layer = (T >> 1) & 1;    // 0 or 1
    const int half  = T & 1;           // K-half 0/1
    const int sub   = T & 3;           // 0: h0 writer lane, 2: h1 writer lane
    const int wv    = T >> 6;          // wave id 0..7

    // ---- init: x row to LDS (coalesced int4) ----
    const int4* xr = (const int4*)(x + b * L_LEN);
    int4* xd = (int4*)xsm;
    for (int i = T; i < L_LEN / 4; i += TPB) xd[i] = xr[i];

    // R[i][m] = elu(W_in[i][m]); prev is one-hot so r = elu(row of W_in)
    if (T < 2 * HID) {
        float v = W_in[T];
        Rsm[T] = v > 0.f ? v : (__expf(v) - 1.f);
    }
    if (T < 2 * 2 * 132) ((float*)hbuf)[T] = 0.f;   // zero carry (tail is
    // overwritten at t=0 before first read; pads never read)
    if (T < 16) ((float*)gpart)[T] = 0.f;
    if (T < 8)  accbuf[T] = 0.f;

    // ---- weights to registers: w[j] = W_c[layer][half*64+j][m] ----
    float w[64];
    const float* wp = W_c + layer * HID * HID + (half * 64) * HID + m;
    #pragma unroll
    for (int j = 0; j < 64; ++j) w[j] = wp[j * HID];

    const float wout = W_out[m];      // W_out is [128][1]
    const float b0   = b_out[0];

    const float* hb0 = &hbuf[0][layer][half * 64];
    const float* hb1 = &hbuf[1][layer][half * 64];

    float acc_lp = 0.f;

    __syncthreads();

    for (int t = 0; t < L_LEN; ++t) {
        const int p = t & 1;
        const float* hr = p ? hb1 : hb0;

        // 64-element partial dot: 16x ds_read_b128 (broadcast) + 64 FMA
        float a0 = 0.f, a1 = 0.f, a2 = 0.f, a3 = 0.f;
        #pragma unroll
        for (int jj = 0; jj < 16; ++jj) {
            float4 hv = *(const float4*)(hr + jj * 4);
            a0 = fmaf(hv.x, w[jj * 4 + 0], a0);
            a1 = fmaf(hv.y, w[jj * 4 + 1], a1);
            a2 = fmaf(hv.z, w[jj * 4 + 2], a2);
            a3 = fmaf(hv.w, w[jj * 4 + 3], a3);
        }
        float acc = (a0 + a1) + (a2 + a3);
        acc += __shfl_xor(acc, 1, 64);                 // join K halves

        // elu
        float a = acc > 0.f ? acc : (__expf(acc) - 1.f);

        const int tm1 = t > 0 ? t - 1 : 0;
        const int xp  = xsm[tm1];
        float radd = (t > 0) ? Rsm[xp * HID + m] : 0.f;

        float hval = (layer == 0) ? (a + radd) : a;    // h0_new on layer0 lanes
        float h0n  = __shfl_xor(hval, 2, 64);          // pull h0_new to layer1 lanes
        float h1n  = hval + h0n;                       // h1_new (valid on sub==2)

        float (*hw)[132] = hbuf[p ^ 1];
        if (sub == 0) hw[0][m] = hval;
        if (sub == 2) hw[1][m] = h1n;

        // logit partial: g = sum_m h1_new[m] * W_out[m]; wave-level tree
        float gv = (sub == 2) ? h1n * wout : 0.f;
        gv += __shfl_xor(gv, 4, 64);
        gv += __shfl_xor(gv, 8, 64);
        gv += __shfl_xor(gv, 16, 64);
        gv += __shfl_xor(gv, 32, 64);
        if ((T & 63) == 2) gpart[p][wv] = gv;

        // rotating consumer: finish step t-1's logit -> log-prob
        if (t > 0 && T == (((t - 1) & 7) << 6)) {
            float s = 0.f;
            #pragma unroll
            for (int i2 = 0; i2 < 8; ++i2) s += gpart[p ^ 1][i2];
            float g   = s + b0;
            float lse = fmaxf(g, 0.f) + log1pf(__expf(-fabsf(g)));
            float lp  = 0.5f * ((xp ? g : 0.f) - lse);   // xp == x[t-1]
            acc_lp += lp;
        }

        __syncthreads();
    }

    // epilogue: consume final step's logit (parity of L-1 is 1)
    if (T == 0) {
        float s = 0.f;
        #pragma unroll
        for (int i2 = 0; i2 < 8; ++i2) s += gpart[1][i2];
        float g   = s + b0;
        float lse = fmaxf(g, 0.f) + log1pf(__expf(-fabsf(g)));
        int   xt  = xsm[L_LEN - 1];
        float lp  = 0.5f * ((xt ? g : 0.f) - lse);
        acc_lp += lp;
    }
    if ((T & 63) == 0) accbuf[wv] = acc_lp;
    __syncthreads();
    if (T == 0) {
        float s = 0.f;
        #pragma unroll
        for (int i2 = 0; i2 < 8; ++i2) s += accbuf[i2];
        out[b] = s;
    }
}

extern "C" void kernel_launch(void* const* d_in, const int* in_sizes, int n_in,
                              void* d_out, int out_size, void* d_ws, size_t ws_size,
                              hipStream_t stream)
{
    const int*   x     = (const int*)  d_in[0];
    const float* W_in  = (const float*)d_in[1];
    const float* W_c   = (const float*)d_in[2];
    const float* W_out = (const float*)d_in[3];
    const float* b_out = (const float*)d_in[4];
    float* out = (float*)d_out;

    rnn_fused_kernel<<<256, TPB, 0, stream>>>(x, W_in, W_c, W_out, b_out, out);
}

// Round 3
// 4049.813 us; speedup vs baseline: 1.0580x; 1.0580x over previous
//
#include <hip/hip_runtime.h>
#include <hip/hip_bf16.h>

// RNN1DGeneral via MFMA: B=256 blocks (1 batch each), 128 threads (2 waves).
// Wave w computes BOTH layers for output half [64w,64w+64):
//   h0[t] = elu(h0[t-1]@W0) + R[x[t-1]];  h1[t] = elu(h1[t-1]@W1) + h0[t]
// Weights = static B-fragments in VGPRs (128 VGPR). h = 256 bf16 in LDS,
// parity double-buffered; A-frag = 1 ds_read_b128 per (layer,ktile), the
// MFMA broadcasts h across all 16 rows (every C row is a valid copy).
// One __syncthreads per step. Logit for step t-1 consumed by wave0 during
// step t's A-read latency shadow.

#define L_LEN 4096
#define HID   128
#define TPB   128

typedef float f32x4 __attribute__((ext_vector_type(4)));
typedef short s16x8 __attribute__((ext_vector_type(8)));   // 8 bf16 (4 VGPRs), per guide §3

__device__ __forceinline__ float eluf(float v) {
    return v > 0.f ? v : (__expf(v) - 1.f);
}
__device__ __forceinline__ unsigned short f2bf(float v) {
    __hip_bfloat16 h = __float2bfloat16(v);   // RNE
    union { __hip_bfloat16 b; unsigned short u; } cv;
    cv.b = h;
    return cv.u;
}

__global__ __launch_bounds__(TPB, 1)
void rnn_mfma_kernel(const int*   __restrict__ x,
                     const float* __restrict__ W_in,
                     const float* __restrict__ W_c,
                     const float* __restrict__ W_out,
                     const float* __restrict__ b_out,
                     float*       __restrict__ out)
{
    __shared__ __align__(16) int            xsm[L_LEN];          // 16 KB
    __shared__ __align__(16) unsigned short hsm[2][2][HID];      // [parity][layer][k] bf16 bits
    __shared__ float gpart[2][2];                                // [parity][wave] logit partials

    const int T  = threadIdx.x;
    const int b  = blockIdx.x;
    const int w  = T >> 6;      // wave 0/1 -> N-half
    const int l  = T & 63;
    const int lr = l & 15;      // col within 16-tile
    const int lg = l >> 4;      // k-group 0..3

    // ---- stage x (coalesced), zero initial h state (parity 0) ----
    const int4* xr = (const int4*)(x + b * L_LEN);
    for (int i = T; i < L_LEN / 4; i += TPB) ((int4*)xsm)[i] = xr[i];
    for (int i = T; i < 2 * HID; i += TPB) ((unsigned short*)hsm[0])[i] = 0;

    // ---- static B-fragments: Bf[layer][n][kt][j] = bf16(W_c[layer][k][m]) ----
    // B layout (16x16x32): lane l holds B[k = kt*32 + (l>>4)*8 + j][col = l&15]
    s16x8 Bf[2][4][4];
    #pragma unroll
    for (int layer = 0; layer < 2; ++layer)
      #pragma unroll
      for (int n = 0; n < 4; ++n) {
        const int m = w * 64 + n * 16 + lr;
        #pragma unroll
        for (int kt = 0; kt < 4; ++kt) {
            s16x8 f;
            #pragma unroll
            for (int j = 0; j < 8; ++j) {
                int k = kt * 32 + lg * 8 + j;
                f[j] = (short)f2bf(W_c[(layer * HID + k) * HID + m]);
            }
            Bf[layer][n][kt] = f;
        }
      }

    // per-lane epilogue constants
    float R0[4], R1[4], wo[4];
    #pragma unroll
    for (int n = 0; n < 4; ++n) {
        int m = w * 64 + n * 16 + lr;
        R0[n] = eluf(W_in[m]);          // elu(W_in[0][m])
        R1[n] = eluf(W_in[HID + m]);    // elu(W_in[1][m])
        wo[n] = W_out[m];               // W_out is [128][1]
    }
    const float b0 = b_out[0];

    float acc_lp = 0.f;
    __syncthreads();

    for (int t = 0; t < L_LEN; ++t) {
        const int p = t & 1;

        // ---- A fragments: broadcast h[k] to all 16 rows (1 b128 each) ----
        s16x8 A0[4], A1[4];
        #pragma unroll
        for (int kt = 0; kt < 4; ++kt) {
            A0[kt] = *(const s16x8*)(&hsm[p][0][kt * 32 + lg * 8]);
            A1[kt] = *(const s16x8*)(&hsm[p][1][kt * 32 + lg * 8]);
        }

        const int xp = (t > 0) ? xsm[t - 1] : 0;

        // wave0: consume step t-1's logit in the A-read latency shadow
        if (w == 0 && t > 0) {
            float g   = gpart[p ^ 1][0] + gpart[p ^ 1][1] + b0;
            float lse = fmaxf(g, 0.f) + log1pf(__expf(-fabsf(g)));
            acc_lp += 0.5f * ((xp ? g : 0.f) - lse);   // pairs with x[t-1]
        }

        // ---- MFMA: both layers, this wave's N-half (8 indep K-chains) ----
        f32x4 C0[4], C1[4];
        #pragma unroll
        for (int n = 0; n < 4; ++n) {
            f32x4 c0 = {0.f, 0.f, 0.f, 0.f};
            f32x4 c1 = {0.f, 0.f, 0.f, 0.f};
            #pragma unroll
            for (int kt = 0; kt < 4; ++kt) {
                c0 = __builtin_amdgcn_mfma_f32_16x16x32_bf16(A0[kt], Bf[0][n][kt], c0, 0, 0, 0);
                c1 = __builtin_amdgcn_mfma_f32_16x16x32_bf16(A1[kt], Bf[1][n][kt], c1, 0, 0, 0);
            }
            C0[n] = c0; C1[n] = c1;
        }

        // ---- epilogue: every C row is a valid copy; use reg0 ----
        float gv = 0.f;
        #pragma unroll
        for (int n = 0; n < 4; ++n) {
            float h0 = eluf(C0[n][0]) + ((t > 0) ? (xp ? R1[n] : R0[n]) : 0.f);
            float h1 = eluf(C1[n][0]) + h0;
            if (l < 16) {   // one writer per m; 2-way bank alias = free
                int m = w * 64 + n * 16 + lr;
                hsm[p ^ 1][0][m] = f2bf(h0);
                hsm[p ^ 1][1][m] = f2bf(h1);
            }
            gv = fmaf(h1, wo[n], gv);
        }
        // logit partial over this wave's 64 m: reduce the 16-lane group
        gv += __shfl_xor(gv, 1, 64);
        gv += __shfl_xor(gv, 2, 64);
        gv += __shfl_xor(gv, 4, 64);
        gv += __shfl_xor(gv, 8, 64);
        if (l == 0) gpart[p][w] = gv;

        __syncthreads();
    }

    // final step's logit (parity of L-1 is 1); acc_lp is uniform on wave0
    if (T == 0) {
        float g   = gpart[1][0] + gpart[1][1] + b0;
        float lse = fmaxf(g, 0.f) + log1pf(__expf(-fabsf(g)));
        int   xt  = xsm[L_LEN - 1];
        acc_lp += 0.5f * ((xt ? g : 0.f) - lse);
        out[b] = acc_lp;
    }
}

extern "C" void kernel_launch(void* const* d_in, const int* in_sizes, int n_in,
                              void* d_out, int out_size, void* d_ws, size_t ws_size,
                              hipStream_t stream)
{
    const int*   x     = (const int*)  d_in[0];
    const float* W_in  = (const float*)d_in[1];
    const float* W_c   = (const float*)d_in[2];
    const float* W_out = (const float*)d_in[3];
    const float* b_out = (const float*)d_in[4];
    float* out = (float*)d_out;

    rnn_mfma_kernel<<<256, TPB, 0, stream>>>(x, W_in, W_c, W_out, b_out, out);
}

// Round 5
// 3661.020 us; speedup vs baseline: 1.1704x; 1.1062x over previous
//
#include <hip/hip_runtime.h>
#include <hip/hip_bf16.h>

// RNN1DGeneral batched-MFMA design:
//   16 blocks x 16 batches (MFMA M-dim = batches, 100% useful MACs),
//   256 threads = 4 waves, wave w owns cols [32w, 32w+32) of BOTH layers.
//   h state: LDS [parity][layer][batch][k] bf16, XOR-swizzled (T2) so the
//   ds_read_b128 A-frag loads are bank-balanced; writes are swizzle-matched
//   ds_write_b16. One __syncthreads per step.
//   Logit g[batch] = h1 . W_out via ONE extra MFMA per wave (kt=w slice,
//   wo in col 0 of a B-frag); 16 consumer lanes finish softplus for step
//   t-2 (deferred, off the critical path).
//   x bit-packed in the preamble via __ballot (coalesced, no workspace).

#define L_LEN 4096
#define HID   128
#define NB    16
#define TPB   256
#define WPITCH 129   // xbits LDS pitch (pad: consumer reads col-wise)

typedef float f32x4 __attribute__((ext_vector_type(4)));
typedef short s16x8 __attribute__((ext_vector_type(8)));

__device__ __forceinline__ float eluf(float v) { return v > 0.f ? v : (__expf(v) - 1.f); }
__device__ __forceinline__ unsigned short f2bf(float v) {
    union { __hip_bfloat16 b; unsigned short u; } cv;
    cv.b = __float2bfloat16(v);
    return cv.u;
}

__global__ __launch_bounds__(TPB, 1)
void rnn16_kernel(const int*   __restrict__ x,
                  const float* __restrict__ W_in,
                  const float* __restrict__ W_c,
                  const float* __restrict__ W_out,
                  const float* __restrict__ b_out,
                  float* __restrict__ out)
{
    __shared__ __align__(16) unsigned short hAf[2 * 2 * NB * HID]; // [q][layer][b][k] 16 KB
    __shared__ unsigned xbsm[NB * WPITCH];                         // 8.25 KB bitwords
    __shared__ float gbuf[2][4][NB];                               // [parity][wave][batch]

    const int T   = threadIdx.x;
    const int w   = T >> 6;      // wave id: cols [32w, 32w+32)
    const int l   = T & 63;
    const int c   = l & 15;      // MFMA row/col lane index
    const int g   = l >> 4;      // k-group
    const int bb0 = blockIdx.x * NB;

    // ---- pack x bits via ballot: 64 coalesced ints -> one 64-bit mask ----
    for (int idx = w; idx < NB * (L_LEN / 64); idx += 4) {
        int batch = idx >> 6;                  // 64 iters per batch
        int pos   = ((idx & 63) << 6) + l;     // position within sequence
        int v     = x[(bb0 + batch) * L_LEN + pos];
        unsigned long long mask = __ballot(v & 1);
        if (l == 0)  xbsm[batch * WPITCH + ((idx & 63) << 1)]     = (unsigned)mask;
        if (l == 32) xbsm[batch * WPITCH + ((idx & 63) << 1) + 1] = (unsigned)(mask >> 32);
    }
    for (int i = T; i < 2 * NB * HID; i += TPB) hAf[i] = 0;   // zero parity-0 h

    // ---- static B fragments: Bf[layer][n][kt], lane holds B[k=kt*32+g*8+j][col] ----
    s16x8 Bf[2][2][4];
    #pragma unroll
    for (int layer = 0; layer < 2; ++layer)
      #pragma unroll
      for (int n = 0; n < 2; ++n) {
        const int col = w * 32 + n * 16 + c;
        #pragma unroll
        for (int kt = 0; kt < 4; ++kt) {
            s16x8 f;
            #pragma unroll
            for (int j = 0; j < 8; ++j) {
                int k = kt * 32 + g * 8 + j;
                f[j] = (short)f2bf(W_c[(layer * HID + k) * HID + col]);
            }
            Bf[layer][n][kt] = f;
        }
      }
    // wo B-frag: col 0 = W_out slice for kt = w
    s16x8 woB;
    #pragma unroll
    for (int j = 0; j < 8; ++j) {
        int k = w * 32 + g * 8 + j;
        woB[j] = (c == 0) ? (short)f2bf(W_out[k]) : (short)0;
    }
    // epilogue constants
    float R0[2], R1[2];
    #pragma unroll
    for (int n = 0; n < 2; ++n) {
        int col = w * 32 + n * 16 + c;
        R0[n] = eluf(W_in[col]);
        R1[n] = eluf(W_in[HID + col]);
    }
    const float b0 = b_out[0];

    float acc = 0.f;
    unsigned xw[4] = {0u, 0u, 0u, 0u};   // R-select bitwords for batches 4g+r

    __syncthreads();

    for (int t = 0; t <= L_LEN; ++t) {
        const int q   = t & 1;                       // parity holding h[t-1]
        const int swz = (c & 7) << 3;
        const int rb0 = ((q * 2 + 0) * NB + c) * HID;
        const int rb1 = ((q * 2 + 1) * NB + c) * HID;

        // ---- A fragments (swizzled b128): lane -> batch c, k = kt*32+g*8.. ----
        s16x8 A1[4];
        #pragma unroll
        for (int kt = 0; kt < 4; ++kt)
            A1[kt] = *(const s16x8*)&hAf[rb1 + ((kt * 32 + g * 8) ^ swz)];

        // ---- logit partial MFMA: g[batch] slice for kt = w (h1[t-1]) ----
        {
            s16x8 Aw = *(const s16x8*)&hAf[rb1 + ((w * 32 + g * 8) ^ swz)];
            f32x4 Cg = {0.f, 0.f, 0.f, 0.f};
            Cg = __builtin_amdgcn_mfma_f32_16x16x32_bf16(Aw, woB, Cg, 0, 0, 0);
            if (c == 0) *(f32x4*)&gbuf[q][w][4 * g] = Cg;   // batch = 4g+reg
        }

        // ---- consumer: finish logit for step s = t-2 (deferred) ----
        if (t >= 2 && T < NB) {
            int s = t - 2;
            float gg = gbuf[q ^ 1][0][T] + gbuf[q ^ 1][1][T]
                     + gbuf[q ^ 1][2][T] + gbuf[q ^ 1][3][T] + b0;
            unsigned cw = xbsm[T * WPITCH + (s >> 5)];
            int bit = (cw >> (s & 31)) & 1;
            float mm  = fmaxf(gg, 0.f);
            float lse = mm + __logf(__expf(gg - mm) + __expf(-mm));
            acc += 0.5f * ((bit ? gg : 0.f) - lse);
        }

        if (t < L_LEN) {
            s16x8 A0[4];
            #pragma unroll
            for (int kt = 0; kt < 4; ++kt)
                A0[kt] = *(const s16x8*)&hAf[rb0 + ((kt * 32 + g * 8) ^ swz)];

            // refresh R-select bitwords every 32 steps
            if (t >= 1 && (((t - 1) & 31) == 0)) {
                int wi = (t - 1) >> 5;
                #pragma unroll
                for (int r = 0; r < 4; ++r) xw[r] = xbsm[(4 * g + r) * WPITCH + wi];
            }

            // ---- h-update MFMAs: both layers, 2 n-tiles ----
            f32x4 C0[2], C1[2];
            #pragma unroll
            for (int n = 0; n < 2; ++n) {
                f32x4 c0 = {0.f, 0.f, 0.f, 0.f};
                f32x4 c1 = {0.f, 0.f, 0.f, 0.f};
                #pragma unroll
                for (int kt = 0; kt < 4; ++kt) {
                    c0 = __builtin_amdgcn_mfma_f32_16x16x32_bf16(A0[kt], Bf[0][n][kt], c0, 0, 0, 0);
                    c1 = __builtin_amdgcn_mfma_f32_16x16x32_bf16(A1[kt], Bf[1][n][kt], c1, 0, 0, 0);
                }
                C0[n] = c0; C1[n] = c1;
            }

            // ---- epilogue: elu + R-add + layer chain, swizzled b16 writes ----
            const int sh = (t - 1) & 31;
            #pragma unroll
            for (int n = 0; n < 2; ++n) {
                const int col = w * 32 + n * 16 + c;
                #pragma unroll
                for (int r = 0; r < 4; ++r) {
                    int bit = (t > 0) ? (int)((xw[r] >> sh) & 1u) : 0;
                    float radd = (t > 0) ? (bit ? R1[n] : R0[n]) : 0.f;
                    float h0 = eluf(C0[n][r]) + radd;
                    float h1 = eluf(C1[n][r]) + h0;
                    int b  = 4 * g + r;
                    int sw = (b & 7) << 3;
                    hAf[(((q ^ 1) * 2 + 0) * NB + b) * HID + (col ^ sw)] = f2bf(h0);
                    hAf[(((q ^ 1) * 2 + 1) * NB + b) * HID + (col ^ sw)] = f2bf(h1);
                }
            }
        }

        __syncthreads();
    }

    // ---- final logit s = L-1 (partials written at t = L into gbuf[0]) ----
    if (T < NB) {
        float gg = gbuf[0][0][T] + gbuf[0][1][T] + gbuf[0][2][T] + gbuf[0][3][T] + b0;
        unsigned cw = xbsm[T * WPITCH + ((L_LEN - 1) >> 5)];
        int bit = (cw >> ((L_LEN - 1) & 31)) & 1;
        float mm  = fmaxf(gg, 0.f);
        float lse = mm + __logf(__expf(gg - mm) + __expf(-mm));
        acc += 0.5f * ((bit ? gg : 0.f) - lse);
        out[bb0 + T] = acc;
    }
}

extern "C" void kernel_launch(void* const* d_in, const int* in_sizes, int n_in,
                              void* d_out, int out_size, void* d_ws, size_t ws_size,
                              hipStream_t stream)
{
    const int*   x     = (const int*)  d_in[0];
    const float* W_in  = (const float*)d_in[1];
    const float* W_c   = (const float*)d_in[2];
    const float* W_out = (const float*)d_in[3];
    const float* b_out = (const float*)d_in[4];
    float* out = (float*)d_out;

    rnn16_kernel<<<16, TPB, 0, stream>>>(x, W_in, W_c, W_out, b_out, out);
}

// Round 6
// 3129.346 us; speedup vs baseline: 1.3692x; 1.1699x over previous
//
#include <hip/hip_runtime.h>
#include <hip/hip_bf16.h>

// RNN1DGeneral, swapped-MFMA orientation:
//   16 blocks x 16 batches, 256 threads (4 waves), wave w owns output cols
//   [32w, 32w+32) of BOTH layers.
//   MFMA computes D[col][batch] = W^T . h : A = W (static regs, verified
//   B-frag packing), B = h (verified swizzled ds_read_b128). C layout:
//   batch = lane&15 (fixed per thread), cols = 4g+r (consecutive) ->
//   h writes are 4 aligned ds_write_b64 (conflict-free), one x-bit/thread.
//   Logit g[batch] via one MFMA per wave reusing B1[kt=w] (wo on A row 0).
//   Loop t=1..4096 (t=0 provably keeps h=0; its log-prob flows through the
//   normal gbuf pipeline), unrolled x2 with compile-time parity.
//   One __syncthreads per step.

#define L_LEN 4096
#define HID   128
#define NB    16
#define TPB   256
#define WPITCH 129

typedef float f32x4 __attribute__((ext_vector_type(4)));
typedef short s16x8 __attribute__((ext_vector_type(8)));
typedef short s16x4 __attribute__((ext_vector_type(4)));

__device__ __forceinline__ float eluf(float v) { return v > 0.f ? v : (__expf(v) - 1.f); }
__device__ __forceinline__ unsigned short f2bf(float v) {
    union { __hip_bfloat16 b; unsigned short u; } cv;
    cv.b = __float2bfloat16(v);
    return cv.u;
}

__global__ __launch_bounds__(TPB, 1)
void rnn_swap_kernel(const int*   __restrict__ x,
                     const float* __restrict__ W_in,
                     const float* __restrict__ W_c,
                     const float* __restrict__ W_out,
                     const float* __restrict__ b_out,
                     float* __restrict__ out)
{
    __shared__ __align__(16) unsigned short hAf[2][2][NB][HID]; // [q][layer][b][k] 16KB
    __shared__ unsigned xbsm[NB * WPITCH];                      // bitwords 8.25KB
    __shared__ float gbuf[2][4][NB];                            // [q][wave][batch]

    const int T = threadIdx.x;
    const int w = T >> 6, l = T & 63, c = l & 15, g = l >> 4;
    const int bb0 = blockIdx.x * NB;
    const int swz = (c & 7) << 3;

    // ---- pack x bits via ballot (coalesced) ----
    for (int idx = w; idx < NB * (L_LEN / 64); idx += 4) {
        int batch = idx >> 6;
        int pos   = ((idx & 63) << 6) + l;
        int v     = x[(bb0 + batch) * L_LEN + pos];
        unsigned long long mask = __ballot(v & 1);
        if (l == 0)  xbsm[batch * WPITCH + ((idx & 63) << 1)]     = (unsigned)mask;
        if (l == 32) xbsm[batch * WPITCH + ((idx & 63) << 1) + 1] = (unsigned)(mask >> 32);
    }
    for (int i = T; i < 2 * 2 * NB * HID; i += TPB) ((unsigned short*)hAf)[i] = 0;

    // ---- static A fragments (W): lane holds A[row=c][k=kt*32+g*8+j] ----
    s16x8 Af[2][2][4];
    #pragma unroll
    for (int layer = 0; layer < 2; ++layer)
      #pragma unroll
      for (int mt = 0; mt < 2; ++mt) {
        const int col = w * 32 + mt * 16 + c;
        #pragma unroll
        for (int kt = 0; kt < 4; ++kt) {
            s16x8 f;
            #pragma unroll
            for (int j = 0; j < 8; ++j)
                f[j] = (short)f2bf(W_c[(layer * HID + kt * 32 + g * 8 + j) * HID + col]);
            Af[layer][mt][kt] = f;
        }
      }
    // wo on A row 0, k-slice kt = w
    s16x8 woA;
    #pragma unroll
    for (int j = 0; j < 8; ++j)
        woA[j] = (c == 0) ? (short)f2bf(W_out[w * 32 + g * 8 + j]) : (short)0;

    // per-thread epilogue constants: cols = w*32 + mt*16 + 4g + r
    float R0v[2][4], R1v[2][4];
    #pragma unroll
    for (int mt = 0; mt < 2; ++mt)
      #pragma unroll
      for (int r = 0; r < 4; ++r) {
        int co = w * 32 + mt * 16 + 4 * g + r;
        R0v[mt][r] = eluf(W_in[co]);
        R1v[mt][r] = eluf(W_in[HID + co]);
      }
    const float b0 = b_out[0];

    // precomputed LDS short-offsets
    const int ro0 = (0 * 32 + g * 8) ^ swz, ro1 = (1 * 32 + g * 8) ^ swz;
    const int ro2 = (2 * 32 + g * 8) ^ swz, ro3 = (3 * 32 + g * 8) ^ swz;
    const int wo0 = (w * 32 + 0 * 16 + 4 * g) ^ swz;
    const int wo1 = (w * 32 + 1 * 16 + 4 * g) ^ swz;

    float acc = 0.f;
    unsigned xw = 0;

    __syncthreads();

#define STEP(T_, Q_) do {                                                     \
    const int t_ = (T_);                                                      \
    s16x8 B1v[4], B0v[4];                                                     \
    B1v[0] = *(const s16x8*)&hAf[Q_][1][c][ro0];                              \
    B1v[1] = *(const s16x8*)&hAf[Q_][1][c][ro1];                              \
    B1v[2] = *(const s16x8*)&hAf[Q_][1][c][ro2];                              \
    B1v[3] = *(const s16x8*)&hAf[Q_][1][c][ro3];                              \
    if (t_ < L_LEN) {                                                         \
        B0v[0] = *(const s16x8*)&hAf[Q_][0][c][ro0];                          \
        B0v[1] = *(const s16x8*)&hAf[Q_][0][c][ro1];                          \
        B0v[2] = *(const s16x8*)&hAf[Q_][0][c][ro2];                          \
        B0v[3] = *(const s16x8*)&hAf[Q_][0][c][ro3];                          \
        if (((t_ - 1) & 31) == 0) xw = xbsm[c * WPITCH + ((t_ - 1) >> 5)];    \
    }                                                                         \
    {   /* logit MFMA for h1[t-1]: reuse B1v[w] */                            \
        s16x8 Bw = (w == 0) ? B1v[0] : (w == 1) ? B1v[1]                      \
                 : (w == 2) ? B1v[2] : B1v[3];                                \
        f32x4 Cg = {0.f, 0.f, 0.f, 0.f};                                      \
        Cg = __builtin_amdgcn_mfma_f32_16x16x32_bf16(woA, Bw, Cg, 0, 0, 0);   \
        if (g == 0) gbuf[Q_][w][c] = Cg[0];                                   \
    }                                                                         \
    if (t_ > 1 && T < NB) {   /* consume step s = t-2 */                      \
        int s = t_ - 2;                                                       \
        float gg = gbuf[Q_ ^ 1][0][T] + gbuf[Q_ ^ 1][1][T]                    \
                 + gbuf[Q_ ^ 1][2][T] + gbuf[Q_ ^ 1][3][T] + b0;              \
        unsigned cw = xbsm[T * WPITCH + (s >> 5)];                            \
        int bit = (cw >> (s & 31)) & 1;                                       \
        float mm  = fmaxf(gg, 0.f);                                           \
        float lse = mm + __logf(__expf(gg - mm) + __expf(-mm));               \
        acc += 0.5f * ((bit ? gg : 0.f) - lse);                               \
    }                                                                         \
    if (t_ < L_LEN) {                                                         \
        f32x4 C0v[2], C1v[2];                                                 \
        _Pragma("unroll")                                                     \
        for (int mt = 0; mt < 2; ++mt) {                                      \
            f32x4 c0 = {0.f, 0.f, 0.f, 0.f};                                  \
            f32x4 c1 = {0.f, 0.f, 0.f, 0.f};                                  \
            _Pragma("unroll")                                                 \
            for (int kt = 0; kt < 4; ++kt) {                                  \
                c0 = __builtin_amdgcn_mfma_f32_16x16x32_bf16(                 \
                        Af[0][mt][kt], B0v[kt], c0, 0, 0, 0);                 \
                c1 = __builtin_amdgcn_mfma_f32_16x16x32_bf16(                 \
                        Af[1][mt][kt], B1v[kt], c1, 0, 0, 0);                 \
            }                                                                 \
            C0v[mt] = c0; C1v[mt] = c1;                                       \
        }                                                                     \
        const int bit = (int)((xw >> ((t_ - 1) & 31)) & 1u);                  \
        _Pragma("unroll")                                                     \
        for (int mt = 0; mt < 2; ++mt) {                                      \
            s16x4 p0, p1;                                                     \
            _Pragma("unroll")                                                 \
            for (int r = 0; r < 4; ++r) {                                     \
                float h0 = eluf(C0v[mt][r]) + (bit ? R1v[mt][r] : R0v[mt][r]);\
                float h1 = eluf(C1v[mt][r]) + h0;                             \
                p0[r] = (short)f2bf(h0);                                      \
                p1[r] = (short)f2bf(h1);                                      \
            }                                                                 \
            const int wof = (mt == 0) ? wo0 : wo1;                            \
            *(s16x4*)&hAf[Q_ ^ 1][0][c][wof] = p0;                            \
            *(s16x4*)&hAf[Q_ ^ 1][1][c][wof] = p1;                            \
        }                                                                     \
    }                                                                         \
    __syncthreads();                                                          \
} while (0)

    for (int t = 1; t <= L_LEN; t += 2) {
        STEP(t, 1);
        STEP(t + 1, 0);
    }
#undef STEP

    // final: consume step s = L-1 (logit written at t = 4096, parity 0)
    if (T < NB) {
        float gg = gbuf[0][0][T] + gbuf[0][1][T] + gbuf[0][2][T] + gbuf[0][3][T] + b0;
        unsigned cw = xbsm[T * WPITCH + ((L_LEN - 1) >> 5)];
        int bit = (cw >> ((L_LEN - 1) & 31)) & 1;
        float mm  = fmaxf(gg, 0.f);
        float lse = mm + __logf(__expf(gg - mm) + __expf(-mm));
        acc += 0.5f * ((bit ? gg : 0.f) - lse);
        out[bb0 + T] = acc;
    }
}

extern "C" void kernel_launch(void* const* d_in, const int* in_sizes, int n_in,
                              void* d_out, int out_size, void* d_ws, size_t ws_size,
                              hipStream_t stream)
{
    const int*   x     = (const int*)  d_in[0];
    const float* W_in  = (const float*)d_in[1];
    const float* W_c   = (const float*)d_in[2];
    const float* W_out = (const float*)d_in[3];
    const float* b_out = (const float*)d_in[4];
    float* out = (float*)d_out;

    rnn_swap_kernel<<<16, TPB, 0, stream>>>(x, W_in, W_c, W_out, b_out, out);
}